// Round 8
// baseline (151.900 us; speedup 1.0000x reference)
//
#include <hip/hip_runtime.h>
#include <math.h>

#define NB 2
#define NA 128
#define KD 32
#define LS 36            // LDS row stride: conflict-free float4 row/col access
#define BN (NB*NA)       // 256 agents total = grid size (<= 256 CUs: co-resident)
#define EPSV 1e-8f

// Cross-block scratch (only what must cross the in-kernel barrier).
__device__ __align__(16) float g_Q[BN*KD*KD];   // E^T (Sig+eps)^-1 E
__device__ __align__(16) float g_v[BN*KD];      // v = E^T mu
__device__ __align__(16) float g_u[BN*KD];      // u = Q v
__device__ __align__(16) float g_c[BN];         // 0.5*(v^T Q v + ld - K)
__device__ int g_cnt = 0;                       // barrier arrival counter
__device__ int g_gen = 0;                       // barrier generation (monotonic)

// agent-phase LDS float offsets
#define O_M   0
#define O_X   1152      // unscaled X
#define O_X2  2304      // unscaled X^2
#define O_X4  3456      // scaled X^4
#define O_B1  4608      // B-poly (dead after P3)
#define O_B2  5760      // ME = M*E
#define O_E   6912
#define O_F   8064      // squaring ping-pong
#define O_W   9216      // W = L^-1 E
#define O_T   10368     // T' = E^T(Sig+eps)E + v v^T  (stays in LDS)
#define O_MU  11520     // 32
#define O_VV  11552     // 32
#define O_DG  11584     // 4 per-wave norm partials
#define O_LD  11588     // 1
#define O_P   11592     // 256: u-partials [32][8]
#define O_TOT 11848     // ~47.4 KB
// pair-phase overlays (0..4767: sM/sX/sX2/sX4/B1-head all dead by then)
#define O_SV  0         // 4096: all v of this batch
#define O_SKL 4096      // 128
#define O_SBE 4224      // 128
#define O_SC  4352      // 128
#define O_SP  4480      // 256: [8][32] aggregation partials
#define O_SW  4736      // 32  (ends 4768)

__device__ __forceinline__ float rdlane(float x, int l) {
  return __int_as_float(__builtin_amdgcn_readlane(__float_as_int(x), l));
}
__device__ __forceinline__ float d4(float4 a, float4 b) {
  return a.x*b.x + a.y*b.y + a.z*b.z + a.w*b.w;
}

// acc[m] += sum_q A[r0][q] * B[q][c0+m], 4 outputs (LS-strided LDS tiles)
__device__ __forceinline__ void mm4(const float* A, const float* B,
                                    int r0, int c0, float acc[4]) {
  #pragma unroll
  for (int q4 = 0; q4 < KD; q4 += 4) {
    const float4 a4 = *(const float4*)&A[r0*LS + q4];
    const float ar[4] = {a4.x, a4.y, a4.z, a4.w};
    #pragma unroll
    for (int u = 0; u < 4; ++u) {
      const float4 b4 = *(const float4*)&B[(q4+u)*LS + c0];
      acc[0] += ar[u]*b4.x; acc[1] += ar[u]*b4.y;
      acc[2] += ar[u]*b4.z; acc[3] += ar[u]*b4.w;
    }
  }
}

__global__ __launch_bounds__(256, 1) void fused_kernel(
    const float* __restrict__ mu_q, const float* __restrict__ sigma_q,
    const float* __restrict__ phi, const float* __restrict__ gen,
    float* __restrict__ out) {
  __shared__ __align__(16) float buf[O_TOT];
  const int g = blockIdx.x;
  const int b = g >> 7;
  const int i = g & (NA - 1);
  const int tid = threadIdx.x;
  const int e0 = tid * 4;
  const int r0 = e0 >> 5;
  const int c0 = e0 & 31;          // 4 consecutive cols

  // ================= agent phase =================
  const float p0 = phi[g*3+0], p1 = phi[g*3+1], p2 = phi[g*3+2];
  if (tid < KD) buf[O_MU + tid] = mu_q[g*KD + tid];
  float x[4];
  {
    const float4 sg = *(const float4*)(sigma_q + (size_t)g*1024 + e0);
    const float4 g0 = *(const float4*)(gen + e0);
    const float4 g1 = *(const float4*)(gen + 1024 + e0);
    const float4 g2 = *(const float4*)(gen + 2048 + e0);
    x[0] = p0*g0.x + p1*g1.x + p2*g2.x;
    x[1] = p0*g0.y + p1*g1.y + p2*g2.y;
    x[2] = p0*g0.z + p1*g1.z + p2*g2.z;
    x[3] = p0*g0.w + p1*g1.w + p2*g2.w;
    const float sgv[4] = {sg.x, sg.y, sg.z, sg.w};
    #pragma unroll
    for (int m = 0; m < 4; ++m) {
      buf[O_X + r0*LS + c0 + m] = x[m];
      buf[O_M + r0*LS + c0 + m] = sgv[m] + ((r0 == c0 + m) ? EPSV : 0.f);
    }
  }
  {
    float nrm = x[0]*x[0] + x[1]*x[1] + x[2]*x[2] + x[3]*x[3];
    #pragma unroll
    for (int o = 1; o < 64; o <<= 1) nrm += __shfl_xor(nrm, o);
    if ((tid & 63) == 0) buf[O_DG + (tid >> 6)] = nrm;
  }
  __syncthreads();

  const float anorm = sqrtf(buf[O_DG] + buf[O_DG+1] + buf[O_DG+2] + buf[O_DG+3]);
  int s = 0;
  if (anorm > 1.f) { s = (int)ceilf(log2f(anorm)); s = min(s, 15); }
  const float sc1 = exp2f((float)(-s));
  const float sc2 = sc1*sc1, sc3 = sc2*sc1, sc4 = sc2*sc2;

  // P1: X2u = Xu*Xu (unscaled)
  float a2[4] = {0.f,0.f,0.f,0.f};
  mm4(buf + O_X, buf + O_X, r0, c0, a2);
  #pragma unroll
  for (int m = 0; m < 4; ++m) buf[O_X2 + r0*LS + c0 + m] = a2[m];
  __syncthreads();

  // P2: X3u, X4u; fold scales; B = c4 I + c5 Xs + c6 X2s + c7 X3s
  const float C4 = 1.f/24.f, C5 = 1.f/120.f, C6 = 1.f/720.f, C7 = 1.f/5040.f;
  float x3s[4];
  {
    float a3[4] = {0.f,0.f,0.f,0.f}, a4[4] = {0.f,0.f,0.f,0.f};
    mm4(buf + O_X2, buf + O_X,  r0, c0, a3);
    mm4(buf + O_X2, buf + O_X2, r0, c0, a4);
    #pragma unroll
    for (int m = 0; m < 4; ++m) {
      const float dlt = (r0 == c0 + m) ? 1.f : 0.f;
      x3s[m] = a3[m]*sc3;
      buf[O_X4 + r0*LS + c0 + m] = a4[m]*sc4;
      buf[O_B1 + r0*LS + c0 + m] =
          C4*dlt + C5*(x[m]*sc1) + C6*(a2[m]*sc2) + C7*x3s[m];
    }
  }
  __syncthreads();

  // P3: E = (I + Xs + X2s/2 + X3s/6) + B*X4s
  {
    float u[4] = {0.f,0.f,0.f,0.f};
    mm4(buf + O_B1, buf + O_X4, r0, c0, u);
    #pragma unroll
    for (int m = 0; m < 4; ++m) {
      const float dlt = (r0 == c0 + m) ? 1.f : 0.f;
      buf[O_E + r0*LS + c0 + m] =
          dlt + x[m]*sc1 + 0.5f*(a2[m]*sc2) + (1.f/6.f)*x3s[m] + u[m];
    }
  }
  __syncthreads();

  // squarings: E <- E*E, s times
  float* pe = buf + O_E;
  float* po = buf + O_F;
  for (int t = 0; t < s; ++t) {
    float ac[4] = {0.f,0.f,0.f,0.f};
    mm4(pe, pe, r0, c0, ac);
    #pragma unroll
    for (int m = 0; m < 4; ++m) po[r0*LS + c0 + m] = ac[m];
    __syncthreads();
    float* tp = pe; pe = po; po = tp;
  }

  // chol+subst (tid<64, duplicated halves) || v = E^T mu (64..95) || ME (128..255)
  if (tid < 64) {
    const int ci = tid & 31;
    float acc[KD];
    #pragma unroll
    for (int r = 0; r < KD; ++r) acc[r] = pe[r*LS + ci];   // E column ci
    float row[KD];
    #pragma unroll
    for (int q4 = 0; q4 < KD; q4 += 4) {
      const float4 m4 = *(const float4*)&buf[O_M + ci*LS + q4];
      row[q4] = m4.x; row[q4+1] = m4.y; row[q4+2] = m4.z; row[q4+3] = m4.w;
    }
    float Lr[KD], dinv[KD];
    float dprod = 1.f;
    #pragma unroll
    for (int j = 0; j < KD; ++j) {
      const float djj = rdlane(row[j], j);
      const float d = sqrtf(djj);
      const float rin = 1.f / d;
      dprod *= d;
      dinv[j] = rin;
      const float lij = row[j] * rin;       // valid for lanes ci >= j
      Lr[j] = lij;
      #pragma unroll
      for (int q = j + 1; q < KD; ++q)
        row[q] = fmaf(-lij, rdlane(lij, q), row[q]);
    }
    if (tid == 0) buf[O_LD] = 2.f * logf(dprod);
    #pragma unroll
    for (int q = 0; q < KD; ++q) {          // W[:,ci] = L^-1 E[:,ci]
      const float wq = acc[q] * dinv[q];
      acc[q] = wq;
      #pragma unroll
      for (int r = q + 1; r < KD; ++r)
        acc[r] = fmaf(-rdlane(Lr[q], r), wq, acc[r]);
    }
    #pragma unroll
    for (int r = 0; r < KD; ++r) buf[O_W + r*LS + ci] = acc[r];
  } else if (tid < 96) {
    const int c = tid - 64;                  // v = E^T mu
    float va = 0.f;
    #pragma unroll
    for (int r = 0; r < KD; ++r) va += pe[r*LS + c] * buf[O_MU + r];
    g_v[g*KD + c] = va;
    buf[O_VV + c] = va;
  } else if (tid >= 128) {
    const int t8 = (tid - 128) * 8;          // ME = M*E -> O_B2
    const int rm = t8 >> 5, cm = t8 & 31;
    float a[8] = {0.f,0.f,0.f,0.f,0.f,0.f,0.f,0.f};
    #pragma unroll
    for (int q4 = 0; q4 < KD; q4 += 4) {
      const float4 a4 = *(const float4*)&buf[O_M + rm*LS + q4];
      const float ar[4] = {a4.x, a4.y, a4.z, a4.w};
      #pragma unroll
      for (int u = 0; u < 4; ++u) {
        const float4 b0 = *(const float4*)&pe[(q4+u)*LS + cm];
        const float4 b1 = *(const float4*)&pe[(q4+u)*LS + cm + 4];
        a[0] += ar[u]*b0.x; a[1] += ar[u]*b0.y; a[2] += ar[u]*b0.z; a[3] += ar[u]*b0.w;
        a[4] += ar[u]*b1.x; a[5] += ar[u]*b1.y; a[6] += ar[u]*b1.z; a[7] += ar[u]*b1.w;
      }
    }
    #pragma unroll
    for (int m = 0; m < 8; ++m) buf[O_B2 + rm*LS + cm + m] = a[m];
  }
  __syncthreads();

  // Q = W^T W -> global (+u partials); T' = E^T(ME) + v v^T -> LDS (local only)
  {
    float aq[4] = {0.f,0.f,0.f,0.f}, at[4] = {0.f,0.f,0.f,0.f};
    #pragma unroll
    for (int q = 0; q < KD; ++q) {
      const float wq = buf[O_W + q*LS + r0];
      const float eq = pe[q*LS + r0];
      const float4 wb = *(const float4*)&buf[O_W + q*LS + c0];
      const float4 mb = *(const float4*)&buf[O_B2 + q*LS + c0];
      aq[0] += wq*wb.x; aq[1] += wq*wb.y; aq[2] += wq*wb.z; aq[3] += wq*wb.w;
      at[0] += eq*mb.x; at[1] += eq*mb.y; at[2] += eq*mb.z; at[3] += eq*mb.w;
    }
    const float vr = buf[O_VV + r0];
    float up = 0.f;
    #pragma unroll
    for (int m = 0; m < 4; ++m) {
      const float vc = buf[O_VV + c0 + m];
      buf[O_T + r0*LS + c0 + m] = at[m] + vr*vc;
      up += aq[m]*vc;
    }
    *(float4*)&g_Q[(size_t)g*1024 + r0*KD + c0] = make_float4(aq[0],aq[1],aq[2],aq[3]);
    buf[O_P + r0*8 + (c0 >> 2)] = up;        // u partial
  }
  __syncthreads();

  if (tid < KD) {
    float u = 0.f;
    #pragma unroll
    for (int m = 0; m < 8; ++m) u += buf[O_P + tid*8 + m];
    g_u[g*KD + tid] = u;
    float t = u * buf[O_VV + tid];           // partial of v^T Q v
    #pragma unroll
    for (int o = 1; o < 32; o <<= 1) t += __shfl_xor(t, o);
    if (tid == 0) g_c[g] = 0.5f*(t + buf[O_LD] - (float)KD);
  }

  // ============ grid-wide barrier (spin on device-scope atomics) ============
  __threadfence();                 // release this block's global stores
  __syncthreads();
  if (tid == 0) {
    const int mygen = atomicAdd(&g_gen, 0);   // read before arriving: no race
    const int arr = atomicAdd(&g_cnt, 1);
    if (arr == BN - 1) {
      atomicExch(&g_cnt, 0);                  // reset for next launch
      __threadfence();
      atomicAdd(&g_gen, 1);
    } else {
      while (atomicAdd(&g_gen, 0) == mygen) __builtin_amdgcn_s_sleep(8);
    }
  }
  __syncthreads();
  __threadfence();                 // acquire: invalidate stale L1/L2 views

  // ================= pair phase =================
  {
    const float4* vs = (const float4*)(g_v + (size_t)b*NA*KD);
    float4* dv = (float4*)(buf + O_SV);
    dv[tid]       = vs[tid];
    dv[tid + 256] = vs[tid + 256];
    dv[tid + 512] = vs[tid + 512];
    dv[tid + 768] = vs[tid + 768];
    if (tid < NA) buf[O_SC + tid] = g_c[b*NA + tid];
  }
  const float ldi = buf[O_LD];

  const int lane = tid & 63;
  const int wave = tid >> 6;
  const int k  = lane >> 1;
  const int l0 = (lane & 1) * 16;
  const bool even = (lane & 1) == 0;

  // T'_i row chunk from LDS (lane-constant over the whole j loop)
  float4 t0, t1, t2, t3;
  {
    const float* Tp = buf + O_T + k*LS + l0;
    t0 = *(const float4*)(Tp);     t1 = *(const float4*)(Tp + 4);
    t2 = *(const float4*)(Tp + 8); t3 = *(const float4*)(Tp + 12);
  }
  __syncthreads();

  const float vik = buf[O_SV + i*KD + k];
  const float* Qb = g_Q + (size_t)b*NA*1024 + k*KD + l0;
  const float* ub = g_u + (size_t)b*NA*KD + k;

  #pragma unroll 2
  for (int j = wave; j < NA; j += 4) {
    const float4* Qp = (const float4*)(Qb + (size_t)j*1024);
    const float4 q0 = Qp[0], q1 = Qp[1], q2 = Qp[2], q3 = Qp[3];
    float part = 0.5f*(d4(q0,t0) + d4(q1,t1) + d4(q2,t2) + d4(q3,t3));
    if (even) part = fmaf(-ub[j*KD], vik, part);
    #pragma unroll
    for (int o = 1; o < 64; o <<= 1) part += __shfl_xor(part, o);
    if (lane == 0)
      buf[O_SKL + j] = fmaxf(part + buf[O_SC + j] - 0.5f*ldi, 0.f);
  }
  __syncthreads();

  // softmax over j in one wave: lane holds kl[lane], kl[lane+64]
  if (tid < 64) {
    const float a = buf[O_SKL + tid], c = buf[O_SKL + tid + 64];
    float mn = fminf(a, c);
    #pragma unroll
    for (int o = 1; o < 64; o <<= 1) mn = fminf(mn, __shfl_xor(mn, o));
    const float ea = expf(mn - a);
    const float eb = expf(mn - c);
    float sm = ea + eb;
    #pragma unroll
    for (int o = 1; o < 64; o <<= 1) sm += __shfl_xor(sm, o);
    const float inv = 1.f / sm;
    const float ren = 1.0f / (1.0f + 128.0f * 1e-8f);
    buf[O_SBE + tid]      = (ea*inv + 1e-8f) * ren;
    buf[O_SBE + tid + 64] = (eb*inv + 1e-8f) * ren;
  }
  __syncthreads();

  // w = sum_j beta_j v_j (8 chunks x 32 components)
  {
    const int c = tid >> 5, kk = tid & 31;
    float acc = 0.f;
    #pragma unroll
    for (int jj = 0; jj < 16; ++jj) {
      const int j = c*16 + jj;
      acc += buf[O_SBE + j] * buf[O_SV + j*KD + kk];
    }
    buf[O_SP + c*KD + kk] = acc;
  }
  __syncthreads();
  if (tid < KD) {
    float w = 0.f;
    #pragma unroll
    for (int c2 = 0; c2 < 8; ++c2) w += buf[O_SP + c2*KD + tid];
    buf[O_SW + tid] = w;
  }
  __syncthreads();
  if (tid < KD) {                  // out_i = E_i * w  (E from LDS)
    float acc = 0.f;
    #pragma unroll
    for (int l = 0; l < KD; ++l) acc += pe[tid*LS + l] * buf[O_SW + l];
    out[g*KD + tid] = acc;
  }
}

extern "C" void kernel_launch(void* const* d_in, const int* in_sizes, int n_in,
                              void* d_out, int out_size, void* d_ws, size_t ws_size,
                              hipStream_t stream) {
  (void)in_sizes; (void)n_in; (void)out_size; (void)d_ws; (void)ws_size;
  const float* mu_q    = (const float*)d_in[0];
  const float* sigma_q = (const float*)d_in[1];
  const float* phi     = (const float*)d_in[2];
  const float* gen     = (const float*)d_in[3];
  float* out = (float*)d_out;
  hipLaunchKernelGGL(fused_kernel, dim3(BN), dim3(256), 0, stream,
                     mu_q, sigma_q, phi, gen, out);
}

// Round 10
// 87.104 us; speedup vs baseline: 1.7439x; 1.7439x over previous
//
#include <hip/hip_runtime.h>
#include <math.h>

#define NB 2
#define NA 128
#define KD 32
#define LS 36            // LDS row stride: conflict-free float4 row/col access
#define BN (NB*NA)       // 256 agents total
#define EPSV 1e-8f

// Inter-kernel scratch (graph-capture-safe; fully rewritten every launch).
__device__ __align__(16) float g_Q[BN*KD*KD];   // E^T (Sig+eps)^-1 E
__device__ __align__(16) float g_T[BN*KD*KD];   // T' = E^T (Sig+eps) E + v v^T
__device__ __align__(16) float g_E[BN*KD*KD];   // expm(X)
__device__ __align__(16) float g_v[BN*KD];      // v = E^T mu
__device__ __align__(16) float g_u[BN*KD];      // u = Q v
__device__ __align__(16) float g_ld[BN];        // logdet(Sig+eps)
__device__ __align__(16) float g_c[BN];         // 0.5*(v^T Q v + ld - K)

// agent-phase LDS float offsets
#define O_M   0
#define O_X   1152      // unscaled X
#define O_X2  2304      // unscaled X^2
#define O_X4  3456      // scaled X^4
#define O_B   4608      // B-poly (dead after P3), then ME = M*E
#define O_E   5760
#define O_F   6912      // squaring ping-pong
#define O_W   8064      // W = L^-1 E
#define O_MU  9216      // 32
#define O_VV  9248      // 32
#define O_DG  9280      // 4 per-wave norm partials
#define O_LD  9284      // 1
#define O_P   9288      // 256: u-partials [32][8]
#define O_TOT 9544      // ~38.2 KB

__device__ __forceinline__ float rdlane(float x, int l) {
  return __int_as_float(__builtin_amdgcn_readlane(__float_as_int(x), l));
}
__device__ __forceinline__ float d4(float4 a, float4 b) {
  return a.x*b.x + a.y*b.y + a.z*b.z + a.w*b.w;
}

// acc[m] += sum_q A[r0][q] * B[q][c0+m], 4 outputs (LS-strided LDS tiles)
__device__ __forceinline__ void mm4(const float* A, const float* B,
                                    int r0, int c0, float acc[4]) {
  #pragma unroll
  for (int q4 = 0; q4 < KD; q4 += 4) {
    const float4 a4 = *(const float4*)&A[r0*LS + q4];
    const float ar[4] = {a4.x, a4.y, a4.z, a4.w};
    #pragma unroll
    for (int u = 0; u < 4; ++u) {
      const float4 b4 = *(const float4*)&B[(q4+u)*LS + c0];
      acc[0] += ar[u]*b4.x; acc[1] += ar[u]*b4.y;
      acc[2] += ar[u]*b4.z; acc[3] += ar[u]*b4.w;
    }
  }
}

// ---------------- Kernel 1: per-agent factorizations (256 thr — R3 config) ----
__global__ __launch_bounds__(256, 1) void agent_kernel(
    const float* __restrict__ mu_q, const float* __restrict__ sigma_q,
    const float* __restrict__ phi, const float* __restrict__ gen) {
  __shared__ __align__(16) float buf[O_TOT];
  const int g = blockIdx.x;
  const int tid = threadIdx.x;
  const int e0 = tid * 4;
  const int r0 = e0 >> 5;
  const int c0 = e0 & 31;          // 4 consecutive cols

  const float p0 = phi[g*3+0], p1 = phi[g*3+1], p2 = phi[g*3+2];
  if (tid < KD) buf[O_MU + tid] = mu_q[g*KD + tid];
  float x[4];
  {
    const float4 sg = *(const float4*)(sigma_q + (size_t)g*1024 + e0);
    const float4 g0 = *(const float4*)(gen + e0);
    const float4 g1 = *(const float4*)(gen + 1024 + e0);
    const float4 g2 = *(const float4*)(gen + 2048 + e0);
    x[0] = p0*g0.x + p1*g1.x + p2*g2.x;
    x[1] = p0*g0.y + p1*g1.y + p2*g2.y;
    x[2] = p0*g0.z + p1*g1.z + p2*g2.z;
    x[3] = p0*g0.w + p1*g1.w + p2*g2.w;
    const float sgv[4] = {sg.x, sg.y, sg.z, sg.w};
    #pragma unroll
    for (int m = 0; m < 4; ++m) {
      buf[O_X + r0*LS + c0 + m] = x[m];
      buf[O_M + r0*LS + c0 + m] = sgv[m] + ((r0 == c0 + m) ? EPSV : 0.f);
    }
  }
  {
    float nrm = x[0]*x[0] + x[1]*x[1] + x[2]*x[2] + x[3]*x[3];
    #pragma unroll
    for (int o = 1; o < 64; o <<= 1) nrm += __shfl_xor(nrm, o);
    if ((tid & 63) == 0) buf[O_DG + (tid >> 6)] = nrm;
  }
  __syncthreads();

  const float anorm = sqrtf(buf[O_DG] + buf[O_DG+1] + buf[O_DG+2] + buf[O_DG+3]);
  int s = 0;
  if (anorm > 1.f) { s = (int)ceilf(log2f(anorm)); s = min(s, 15); }
  const float sc1 = exp2f((float)(-s));
  const float sc2 = sc1*sc1, sc3 = sc2*sc1, sc4 = sc2*sc2;

  // P1: X2u = Xu*Xu (unscaled); keep a2 in regs
  float a2[4] = {0.f,0.f,0.f,0.f};
  mm4(buf + O_X, buf + O_X, r0, c0, a2);
  #pragma unroll
  for (int m = 0; m < 4; ++m) buf[O_X2 + r0*LS + c0 + m] = a2[m];
  __syncthreads();

  // P2: X3u, X4u; fold scales; B = c4 I + c5 Xs + c6 X2s + c7 X3s
  const float C4 = 1.f/24.f, C5 = 1.f/120.f, C6 = 1.f/720.f, C7 = 1.f/5040.f;
  float x3s[4];
  {
    float a3[4] = {0.f,0.f,0.f,0.f}, a4[4] = {0.f,0.f,0.f,0.f};
    mm4(buf + O_X2, buf + O_X,  r0, c0, a3);
    mm4(buf + O_X2, buf + O_X2, r0, c0, a4);
    #pragma unroll
    for (int m = 0; m < 4; ++m) {
      const float dlt = (r0 == c0 + m) ? 1.f : 0.f;
      x3s[m] = a3[m]*sc3;
      buf[O_X4 + r0*LS + c0 + m] = a4[m]*sc4;
      buf[O_B + r0*LS + c0 + m] =
          C4*dlt + C5*(x[m]*sc1) + C6*(a2[m]*sc2) + C7*x3s[m];
    }
  }
  __syncthreads();

  // P3: E = (I + Xs + X2s/2 + X3s/6) + B*X4s
  {
    float u[4] = {0.f,0.f,0.f,0.f};
    mm4(buf + O_B, buf + O_X4, r0, c0, u);
    #pragma unroll
    for (int m = 0; m < 4; ++m) {
      const float dlt = (r0 == c0 + m) ? 1.f : 0.f;
      buf[O_E + r0*LS + c0 + m] =
          dlt + x[m]*sc1 + 0.5f*(a2[m]*sc2) + (1.f/6.f)*x3s[m] + u[m];
    }
  }
  __syncthreads();

  // squarings: E <- E*E, s times
  float* pe = buf + O_E;
  float* po = buf + O_F;
  for (int t = 0; t < s; ++t) {
    float ac[4] = {0.f,0.f,0.f,0.f};
    mm4(pe, pe, r0, c0, ac);
    #pragma unroll
    for (int m = 0; m < 4; ++m) po[r0*LS + c0 + m] = ac[m];
    __syncthreads();
    float* tp = pe; pe = po; po = tp;
  }

  // chol+subst (tid<64) || v = E^T mu (64..95) || ME = M*E (128..255)
  if (tid < 64) {
    const int ci = tid & 31;
    float acc[KD];                              // prefetch E column ci
    #pragma unroll
    for (int r = 0; r < KD; ++r) acc[r] = pe[r*LS + ci];
    float row[KD];
    #pragma unroll
    for (int q4 = 0; q4 < KD; q4 += 4) {
      const float4 m4 = *(const float4*)&buf[O_M + ci*LS + q4];
      row[q4] = m4.x; row[q4+1] = m4.y; row[q4+2] = m4.z; row[q4+3] = m4.w;
    }
    float Lr[KD], dinv[KD];
    float dprod = 1.f;
    #pragma unroll
    for (int j = 0; j < KD; ++j) {
      const float djj = rdlane(row[j], j);
      const float d = sqrtf(djj);
      const float rin = 1.f / d;
      dprod *= d;
      dinv[j] = rin;
      const float lij = row[j] * rin;           // valid for lanes ci >= j
      Lr[j] = lij;
      #pragma unroll
      for (int q = j + 1; q < KD; ++q)
        row[q] = fmaf(-lij, rdlane(lij, q), row[q]);
    }
    if (tid == 0) {
      const float ld = 2.f * logf(dprod);
      g_ld[g] = ld;
      buf[O_LD] = ld;
    }
    #pragma unroll
    for (int q = 0; q < KD; ++q) {              // W[:,ci] = L^-1 E[:,ci]
      const float wq = acc[q] * dinv[q];
      acc[q] = wq;
      #pragma unroll
      for (int r = q + 1; r < KD; ++r)
        acc[r] = fmaf(-rdlane(Lr[q], r), wq, acc[r]);
    }
    #pragma unroll
    for (int r = 0; r < KD; ++r) buf[O_W + r*LS + ci] = acc[r];
  } else if (tid < 96) {
    const int c = tid - 64;                     // v = E^T mu
    float va = 0.f;
    #pragma unroll
    for (int r = 0; r < KD; ++r) va += pe[r*LS + c] * buf[O_MU + r];
    g_v[g*KD + c] = va;
    buf[O_VV + c] = va;
  } else if (tid >= 128) {
    const int t8 = (tid - 128) * 8;             // ME = M*E -> O_B
    const int rm = t8 >> 5, cm = t8 & 31;
    float a[8] = {0.f,0.f,0.f,0.f,0.f,0.f,0.f,0.f};
    #pragma unroll
    for (int q4 = 0; q4 < KD; q4 += 4) {
      const float4 a4 = *(const float4*)&buf[O_M + rm*LS + q4];
      const float ar[4] = {a4.x, a4.y, a4.z, a4.w};
      #pragma unroll
      for (int u = 0; u < 4; ++u) {
        const float4 b0 = *(const float4*)&pe[(q4+u)*LS + cm];
        const float4 b1 = *(const float4*)&pe[(q4+u)*LS + cm + 4];
        a[0] += ar[u]*b0.x; a[1] += ar[u]*b0.y; a[2] += ar[u]*b0.z; a[3] += ar[u]*b0.w;
        a[4] += ar[u]*b1.x; a[5] += ar[u]*b1.y; a[6] += ar[u]*b1.z; a[7] += ar[u]*b1.w;
      }
    }
    #pragma unroll
    for (int m = 0; m < 8; ++m) buf[O_B + rm*LS + cm + m] = a[m];
  }
  __syncthreads();

  // Q = W^T W -> global (+u partials); T' = E^T(ME)+vv^T -> global; E -> global
  {
    float aq[4] = {0.f,0.f,0.f,0.f}, at[4] = {0.f,0.f,0.f,0.f};
    #pragma unroll
    for (int q = 0; q < KD; ++q) {
      const float wq = buf[O_W + q*LS + r0];
      const float eq = pe[q*LS + r0];
      const float4 wb = *(const float4*)&buf[O_W + q*LS + c0];
      const float4 mb = *(const float4*)&buf[O_B + q*LS + c0];
      aq[0] += wq*wb.x; aq[1] += wq*wb.y; aq[2] += wq*wb.z; aq[3] += wq*wb.w;
      at[0] += eq*mb.x; at[1] += eq*mb.y; at[2] += eq*mb.z; at[3] += eq*mb.w;
    }
    const float vr = buf[O_VV + r0];
    float up = 0.f;
    #pragma unroll
    for (int m = 0; m < 4; ++m) {
      const float vc = buf[O_VV + c0 + m];
      at[m] += vr * vc;
      up += aq[m] * vc;
    }
    *(float4*)&g_Q[(size_t)g*1024 + r0*KD + c0] = make_float4(aq[0],aq[1],aq[2],aq[3]);
    *(float4*)&g_T[(size_t)g*1024 + r0*KD + c0] = make_float4(at[0],at[1],at[2],at[3]);
    *(float4*)&g_E[(size_t)g*1024 + r0*KD + c0] =
        make_float4(pe[r0*LS + c0], pe[r0*LS + c0 + 1],
                    pe[r0*LS + c0 + 2], pe[r0*LS + c0 + 3]);
    buf[O_P + r0*8 + (c0 >> 2)] = up;           // u partial
  }
  __syncthreads();

  if (tid < KD) {
    float u = 0.f;
    #pragma unroll
    for (int m = 0; m < 8; ++m) u += buf[O_P + tid*8 + m];
    g_u[g*KD + tid] = u;
    float t = u * buf[O_VV + tid];              // partial of v^T Q v
    #pragma unroll
    for (int o = 1; o < 32; o <<= 1) t += __shfl_xor(t, o);
    if (tid == 0) g_c[g] = 0.5f*(t + buf[O_LD] - (float)KD);
  }
}

// ---------------- Kernel 2: pairwise KL + softmax + aggregate (R7 verbatim) ----
__global__ __launch_bounds__(512, 1) void pair_kernel(float* __restrict__ out) {
  const int g = blockIdx.x;
  const int b = g >> 7;
  const int i = g & (NA - 1);
  const int tid = threadIdx.x;
  __shared__ __align__(16) float sv[NA*KD];   // 16 KB
  __shared__ __align__(16) float su[NA*KD];   // 16 KB
  __shared__ float sc[NA];
  __shared__ float skl[NA];
  __shared__ float sbe[NA];
  __shared__ float sp[16*KD];
  __shared__ float sw[KD];

  {
    const float4* vs = (const float4*)(g_v + (size_t)b*NA*KD);
    const float4* us = (const float4*)(g_u + (size_t)b*NA*KD);
    float4* dv = (float4*)sv;
    float4* du = (float4*)su;
    dv[tid]       = vs[tid];
    dv[tid + 512] = vs[tid + 512];
    du[tid]       = us[tid];
    du[tid + 512] = us[tid + 512];
    if (tid < NA) sc[tid] = g_c[b*NA + tid];
  }

  const int lane = tid & 63;
  const int wave = tid >> 6;
  const int k  = lane >> 1;
  const int l0 = (lane & 1) * 16;
  const bool even = (lane & 1) == 0;

  // T'_i row chunk in registers (lane-constant over the whole j loop)
  float4 t0, t1, t2, t3;
  {
    const float4* Tp = (const float4*)(g_T + (size_t)g*1024 + k*KD + l0);
    t0 = Tp[0]; t1 = Tp[1]; t2 = Tp[2]; t3 = Tp[3];
  }
  const float ldi = g_ld[g];
  __syncthreads();

  const float vik = sv[i*KD + k];
  const float* Qb = g_Q + (size_t)b*NA*1024 + k*KD + l0;

  #pragma unroll 2
  for (int j = wave; j < NA; j += 8) {
    const float4* Qp = (const float4*)(Qb + (size_t)j*1024);
    const float4 q0 = Qp[0], q1 = Qp[1], q2 = Qp[2], q3 = Qp[3];
    float part = 0.5f*(d4(q0,t0) + d4(q1,t1) + d4(q2,t2) + d4(q3,t3));
    if (even) part = fmaf(-su[j*KD + k], vik, part);
    #pragma unroll
    for (int o = 1; o < 64; o <<= 1) part += __shfl_xor(part, o);
    if (lane == 0)
      skl[j] = fmaxf(part + sc[j] - 0.5f*ldi, 0.f);
  }
  __syncthreads();

  // softmax over j in one wave: lane holds kl[lane], kl[lane+64]
  if (tid < 64) {
    const float a = skl[tid], c = skl[tid + 64];
    float mn = fminf(a, c);
    #pragma unroll
    for (int o = 1; o < 64; o <<= 1) mn = fminf(mn, __shfl_xor(mn, o));
    const float ea = expf(mn - a);
    const float eb = expf(mn - c);
    float sm = ea + eb;
    #pragma unroll
    for (int o = 1; o < 64; o <<= 1) sm += __shfl_xor(sm, o);
    const float inv = 1.f / sm;
    const float ren = 1.0f / (1.0f + 128.0f * 1e-8f);
    sbe[tid]      = (ea*inv + 1e-8f) * ren;
    sbe[tid + 64] = (eb*inv + 1e-8f) * ren;
  }
  __syncthreads();

  // w = sum_j beta_j v_j (16 chunks x 32 components)
  {
    const int c = tid >> 5, kk = tid & 31;
    float acc = 0.f;
    #pragma unroll
    for (int jj = 0; jj < 8; ++jj) {
      const int j = c*8 + jj;
      acc += sbe[j] * sv[j*KD + kk];
    }
    sp[c*KD + kk] = acc;
  }
  __syncthreads();
  if (tid < KD) {
    float w = 0.f;
    #pragma unroll
    for (int c2 = 0; c2 < 16; ++c2) w += sp[c2*KD + tid];
    sw[tid] = w;
  }
  __syncthreads();
  if (tid < KD) {
    const float* Ei = g_E + (size_t)g*1024 + tid*KD;
    float acc = 0.f;
    #pragma unroll
    for (int l = 0; l < KD; ++l) acc += Ei[l] * sw[l];
    out[g*KD + tid] = acc;
  }
}

extern "C" void kernel_launch(void* const* d_in, const int* in_sizes, int n_in,
                              void* d_out, int out_size, void* d_ws, size_t ws_size,
                              hipStream_t stream) {
  (void)in_sizes; (void)n_in; (void)out_size; (void)d_ws; (void)ws_size;
  const float* mu_q    = (const float*)d_in[0];
  const float* sigma_q = (const float*)d_in[1];
  const float* phi     = (const float*)d_in[2];
  const float* gen     = (const float*)d_in[3];
  float* out = (float*)d_out;
  hipLaunchKernelGGL(agent_kernel, dim3(BN), dim3(256), 0, stream,
                     mu_q, sigma_q, phi, gen);
  hipLaunchKernelGGL(pair_kernel, dim3(BN), dim3(512), 0, stream, out);
}